// Round 8
// baseline (385.645 us; speedup 1.0000x reference)
//
#include <hip/hip_runtime.h>
#include <hip/hip_bf16.h>

#define NN 1024
#define DD 128

// ws layout (floats)
#define WS_COORD 0
#define WS_REG   1
#define WS_BCE   2
#define WS_POSN  3     // [3,19)   per-batch  sum A*(ni+nj)
#define WS_POSC  19    // [19,35)  per-batch  count A>0.5
#define WS_NEGS  35    // [35,51)  per-batch  hinge^2 sum (rare)
#define WS_PDIAG 51    // [51,67)  per-batch  diag positives
#define WS_CROSS 67    // [67,83)  per-batch  sum A*G
#define WS_CNT   83    // [83,99)  per-batch  mask sums
#define WS_NORM  112   // [112, 112+16384) node norms n[b][i] (f32)

typedef __bf16 bf16_t;
typedef bf16_t bf16x4 __attribute__((ext_vector_type(4)));
typedef bf16_t bf16x8 __attribute__((ext_vector_type(8)));
typedef float  f32x4  __attribute__((ext_vector_type(4)));

__device__ __forceinline__ void gload16(const void* g, void* l) {
  __builtin_amdgcn_global_load_lds(
      (const __attribute__((address_space(1))) uint32_t*)g,
      (__attribute__((address_space(3))) uint32_t*)l,
      16, 0, 0);
}

// ---------------- kernel 0: norms + reg + coord + mask counts ----------------
__global__ __launch_bounds__(256) void prep(
    const float* __restrict__ feat, const float* __restrict__ pcoord,
    const float* __restrict__ pts,  const float* __restrict__ masks,
    float* __restrict__ ws) {
  __shared__ float red[4][3];
  const int bx = blockIdx.x;               // 128 blocks: 8 per batch
  const int b = bx >> 3, slab = bx & 7;
  const int t = threadIdx.x, lane = t & 63, w = t >> 6;
  const int sub = lane >> 4, lq = lane & 15;
  const float* fb = feat + (size_t)b * NN * DD;

  float reg = 0.f;
  #pragma unroll
  for (int it = 0; it < 8; ++it) {
    const int node = slab * 128 + it * 16 + w * 4 + sub;
    const float4* src = (const float4*)(fb + (size_t)node * DD) + lq * 2;
    float4 u = src[0], v = src[1];
    float s = u.x*u.x + u.y*u.y + u.z*u.z + u.w*u.w
            + v.x*v.x + v.y*v.y + v.z*v.z + v.w*v.w;
    s += __shfl_xor(s, 1); s += __shfl_xor(s, 2);
    s += __shfl_xor(s, 4); s += __shfl_xor(s, 8);
    if (lq == 0) { ws[WS_NORM + b * NN + node] = s; reg += s; }
  }
  const int ci = bx * 256 + t;
  const float d = pcoord[ci] - pts[ci];
  float coord = d * d;
  float cnt = (t < 128) ? masks[b * NN + slab * 128 + t] : 0.f;

  #pragma unroll
  for (int o = 32; o; o >>= 1) {
    coord += __shfl_xor(coord, o);
    reg   += __shfl_xor(reg, o);
    cnt   += __shfl_xor(cnt, o);
  }
  if (lane == 0) { red[w][0] = coord; red[w][1] = reg; red[w][2] = cnt; }
  __syncthreads();
  if (t == 0) {
    float c = 0.f, r = 0.f, n = 0.f;
    for (int i = 0; i < 4; ++i) { c += red[i][0]; r += red[i][1]; n += red[i][2]; }
    atomicAdd(&ws[WS_COORD], c);
    atomicAdd(&ws[WS_REG], r);
    atomicAdd(&ws[WS_CNT + b], n);
  }
}

// ---------------- kernel 1: chunk-interleaved LDS stream of L,A ----------------
// 1024 blocks x 256 threads (4/CU, all resident). Chunk = 8 KB = 2 rows.
// Stage s: block bx handles chunk c = s*1024 + bx  ->  at any instant the
// grid's reads cover a CONTIGUOUS 8 MB span of L (and of A): uniform HBM
// channel / L3 bank coverage (the r0..r7 kernels all strode power-of-2 gaps
// and never exceeded ~2 TB/s). Batch b = 2s + (bx>>9) varies per stage ->
// per-stage register accumulators (statically indexed).
__global__ __launch_bounds__(256, 4) void lds_stream(
    const float* __restrict__ logits, const float* __restrict__ adj,
    float* __restrict__ ws) {
  __shared__ __align__(16) float4 sL[2][512];   // 16 KB
  __shared__ __align__(16) float4 sA[2][512];   // 16 KB
  __shared__ float red[4][25];
  const int bx = blockIdx.x;            // 1024
  const int hi = bx >> 9;               // 0/1: batch parity offset
  const int r0 = (bx & 511) * 2;        // row pair within each batch matrix
  const int t = threadIdx.x, lane = t & 63, w = t >> 6;
  const float4* Lg = (const float4*)logits;
  const float4* Ag = (const float4*)adj;

  float bce = 0.f;
  float pc[8], pn[8], pd[8];
  #pragma unroll
  for (int s = 0; s < 8; ++s) { pc[s] = 0.f; pn[s] = 0.f; pd[s] = 0.f; }

#define STAGE(s) do {                                                  \
    const size_t c4 = (size_t)((s) * 1024 + bx) * 512;                 \
    gload16(Lg + c4 + t,       &sL[(s) & 1][t]);                       \
    gload16(Lg + c4 + 256 + t, &sL[(s) & 1][t + 256]);                 \
    gload16(Ag + c4 + t,       &sA[(s) & 1][t]);                       \
    gload16(Ag + c4 + 256 + t, &sA[(s) & 1][t + 256]);                 \
  } while (0)

#define ELEM4(L, A, nv, grow, S) do {                                         \
    bce += fmaxf(L.x, 0.f) - L.x * A.x + __logf(1.f + __expf(-fabsf(L.x)));   \
    bce += fmaxf(L.y, 0.f) - L.y * A.y + __logf(1.f + __expf(-fabsf(L.y)));   \
    bce += fmaxf(L.z, 0.f) - L.z * A.z + __logf(1.f + __expf(-fabsf(L.z)));   \
    bce += fmaxf(L.w, 0.f) - L.w * A.w + __logf(1.f + __expf(-fabsf(L.w)));   \
    const float px = (A.x > 0.5f) ? 1.f : 0.f;                                \
    const float py = (A.y > 0.5f) ? 1.f : 0.f;                                \
    const float pz = (A.z > 0.5f) ? 1.f : 0.f;                                \
    const float pw = (A.w > 0.5f) ? 1.f : 0.f;                                \
    pc[S] += px + py + pz + pw;                                               \
    pn[S] += px * (nv + nj.x) + py * (nv + nj.y)                              \
           + pz * (nv + nj.z) + pw * (nv + nj.w);                             \
    if (((grow) >> 2) == t) {                                                 \
      const int e = (grow) & 3;                                               \
      const float av = (e == 0) ? A.x : (e == 1) ? A.y : (e == 2) ? A.z : A.w;\
      pd[S] += (av > 0.5f) ? 1.f : 0.f;                                       \
    } } while (0)

  STAGE(0);
  #pragma unroll
  for (int s = 0; s < 8; ++s) {
    if (s < 7) STAGE(s + 1);            // next contiguous span in flight
    const float* nrm_s = ws + WS_NORM + (2 * s + hi) * NN;
    const float4 nj = ((const float4*)nrm_s)[t];
    const float ni0 = nrm_s[r0];
    const float ni1 = nrm_s[r0 + 1];
    const float4 L0 = sL[s & 1][t];     // compiler inserts the vmcnt wait
    const float4 A0 = sA[s & 1][t];
    const float4 L1 = sL[s & 1][t + 256];
    const float4 A1 = sA[s & 1][t + 256];
    ELEM4(L0, A0, ni0, r0, s);
    ELEM4(L1, A1, ni1, r0 + 1, s);
  }
#undef STAGE
#undef ELEM4

  #pragma unroll
  for (int o = 32; o; o >>= 1) {
    bce += __shfl_xor(bce, o);
    #pragma unroll
    for (int s = 0; s < 8; ++s) {
      pc[s] += __shfl_xor(pc[s], o);
      pn[s] += __shfl_xor(pn[s], o);
      pd[s] += __shfl_xor(pd[s], o);
    }
  }
  if (lane == 0) {
    red[w][0] = bce;
    #pragma unroll
    for (int s = 0; s < 8; ++s) {
      red[w][1 + s] = pc[s]; red[w][9 + s] = pn[s]; red[w][17 + s] = pd[s];
    }
  }
  __syncthreads();
  if (t == 0) {
    float v[25];
    for (int i = 0; i < 25; ++i)
      v[i] = red[0][i] + red[1][i] + red[2][i] + red[3][i];
    atomicAdd(&ws[WS_BCE], v[0]);
    for (int s = 0; s < 8; ++s) {
      const int b = 2 * s + hi;
      atomicAdd(&ws[WS_POSC + b], v[1 + s]);
      atomicAdd(&ws[WS_POSN + b], v[9 + s]);
      atomicAdd(&ws[WS_PDIAG + b], v[17 + s]);
    }
  }
}

// ---------------- kernel 2: row-band gram: cross = sum A*G, neg safety ----------------
// 1024 blocks x 512 threads (2/CU). Block = 16 full rows (one band) of one
// batch: A-band read is 64 KB CONTIGUOUS (vs the old 4-KB-strided tiles).
// G_band = F_band(16x128) x F_chunk^T via MFMA over eight 128-col chunks
// (feat is small & L2-hot). A lives in LDS as bf16 (exact for 0/1).
__global__ __launch_bounds__(512, 4) void gram_band(
    const float* __restrict__ adj, const float* __restrict__ feat,
    float* __restrict__ ws) {
  __shared__ bf16_t Ab[16][1032];     // 33 KB  band of A, bf16 (pad 8)
  __shared__ bf16_t Fb[16][136];      // 4.3 KB band features
  __shared__ bf16_t Fc[128][136];     // 34.8 KB chunk features
  __shared__ float nis[16];
  __shared__ float red[8][2];

  const int bx = blockIdx.x;          // 1024
  const int b = bx >> 6, band = bx & 63;
  const int t = threadIdx.x, lane = t & 63, w = t >> 6;   // 8 waves
  const int lrow = lane & 15, quad = lane >> 4;
  const float* fb = feat + (size_t)b * NN * DD;
  const float* nrm = ws + WS_NORM + b * NN;

  // issue the contiguous A-band loads first (8 float4/thread = 64 KB/block)
  const float4* Abase = (const float4*)(adj + (size_t)b * NN * NN
                                            + (size_t)band * 16 * NN);
  float4 Ar[8];
  #pragma unroll
  for (int i = 0; i < 8; ++i) Ar[i] = Abase[i * 512 + t];

  // stage F_band (16 rows x 128) as bf16: 512 threads x 1 float4
  {
    const int row = t >> 5, d4 = t & 31;
    const float4 v = *(const float4*)(fb + (size_t)(band * 16 + row) * DD + d4 * 4);
    bf16x4 pk;
    pk[0] = (bf16_t)v.x; pk[1] = (bf16_t)v.y; pk[2] = (bf16_t)v.z; pk[3] = (bf16_t)v.w;
    *(bf16x4*)&Fb[row][d4 * 4] = pk;
  }
  if (t < 16) nis[t] = nrm[band * 16 + t];

  // A-band -> LDS bf16
  #pragma unroll
  for (int i = 0; i < 8; ++i) {
    const int u = i * 512 + t;
    const int row = u >> 8, c4 = u & 255;
    bf16x4 pk;
    pk[0] = (bf16_t)Ar[i].x; pk[1] = (bf16_t)Ar[i].y;
    pk[2] = (bf16_t)Ar[i].z; pk[3] = (bf16_t)Ar[i].w;
    *(bf16x4*)&Ab[row][c4 * 4] = pk;
  }
  __syncthreads();

  float cross = 0.f, negs = 0.f;
  for (int cc = 0; cc < 8; ++cc) {
    // stage F chunk: nodes [cc*128, cc*128+128) x 128 dims (L2-hot)
    #pragma unroll
    for (int i = 0; i < 8; ++i) {
      const int u = i * 512 + t;
      const int node = u >> 5, d4 = u & 31;
      const float4 v = *(const float4*)(fb + (size_t)(cc * 128 + node) * DD + d4 * 4);
      bf16x4 pk;
      pk[0] = (bf16_t)v.x; pk[1] = (bf16_t)v.y; pk[2] = (bf16_t)v.z; pk[3] = (bf16_t)v.w;
      *(bf16x4*)&Fc[node][d4 * 4] = pk;
    }
    __syncthreads();

    // MFMA: wave w -> cols [w*16, w*16+16) of this chunk, all 16 band rows
    f32x4 acc = (f32x4){0.f, 0.f, 0.f, 0.f};
    #pragma unroll
    for (int k0 = 0; k0 < DD; k0 += 32) {
      const int kc = k0 + quad * 8;
      const bf16x8 aF = *(const bf16x8*)&Fb[lrow][kc];
      const bf16x8 bF = *(const bf16x8*)&Fc[w * 16 + lrow][kc];
      acc = __builtin_amdgcn_mfma_f32_16x16x32_bf16(aF, bF, acc, 0, 0, 0);
    }

    // consume: C row = quad*4+r (band row), col = w*16+lrow (chunk col)
    const int gcol = cc * 128 + w * 16 + lrow;
    const float njv = nrm[gcol];
    #pragma unroll
    for (int r = 0; r < 4; ++r) {
      const int row = quad * 4 + r;
      const float g = acc[r];
      const float a = (float)Ab[row][gcol];
      if (a > 0.5f) {
        cross += g;
      } else {
        const float sq = nis[row] + njv - 2.f * g;
        if (sq < 1.f && (band * 16 + row) != gcol) {   // essentially never
          const float dd = sqrtf(fmaxf(sq, 1e-12f));
          const float h = 1.f - dd;
          negs += h * h;
        }
      }
    }
    __syncthreads();   // Fc reused next chunk
  }

  #pragma unroll
  for (int o = 32; o; o >>= 1) {
    cross += __shfl_xor(cross, o);
    negs  += __shfl_xor(negs, o);
  }
  if (lane == 0) { red[w][0] = cross; red[w][1] = negs; }
  __syncthreads();
  if (t == 0) {
    float s0 = 0.f, s1 = 0.f;
    for (int i = 0; i < 8; ++i) { s0 += red[i][0]; s1 += red[i][1]; }
    atomicAdd(&ws[WS_CROSS + b], s0);
    atomicAdd(&ws[WS_NEGS + b], s1);
  }
}

// ---------------- finalize ----------------
__global__ void finalize(const float* __restrict__ ws, const float* __restrict__ pcount,
                         float* __restrict__ out) {
  if (threadIdx.x != 0 || blockIdx.x != 0) return;
  const float coord = ws[WS_COORD] / 32768.f;
  const float reg   = ws[WS_REG] / 2097152.f;
  const float edge  = ws[WS_BCE] / 16777216.f;
  float cntl = 0.f, contra = 0.f;
  for (int b = 0; b < 16; ++b) {
    const float d = fabsf(pcount[b] - ws[WS_CNT + b]);
    cntl += (d < 1.f) ? 0.5f * d * d : d - 0.5f;
    const float posc = ws[WS_POSC + b];
    const float pos = (ws[WS_POSN + b] - 2.f * ws[WS_CROSS + b]) / fmaxf(posc, 1.f);
    const float negc = 1024.f * 1024.f - 1024.f - (posc - ws[WS_PDIAG + b]);
    const float neg = ws[WS_NEGS + b] / fmaxf(negc, 1.f);
    contra += pos + neg;
  }
  cntl *= (1.f / 16.f);
  contra *= (1.f / 16.f);
  const float total = coord + 2.f * edge + 0.1f * cntl + 0.001f * reg + 0.1f * contra;
  out[0] = total; out[1] = coord; out[2] = edge;
  out[3] = cntl;  out[4] = reg;   out[5] = contra;
}

extern "C" void kernel_launch(void* const* d_in, const int* in_sizes, int n_in,
                              void* d_out, int out_size, void* d_ws, size_t ws_size,
                              hipStream_t stream) {
  (void)in_sizes; (void)n_in; (void)out_size; (void)ws_size;
  const float* pcoord = (const float*)d_in[0];
  const float* pts    = (const float*)d_in[1];
  const float* logits = (const float*)d_in[2];
  const float* adj    = (const float*)d_in[3];
  const float* masks  = (const float*)d_in[4];
  const float* pcount = (const float*)d_in[5];
  const float* nf     = (const float*)d_in[6];
  float* ws  = (float*)d_ws;
  float* out = (float*)d_out;

  hipMemsetAsync(ws, 0, WS_NORM * sizeof(float), stream);
  prep<<<128, 256, 0, stream>>>(nf, pcoord, pts, masks, ws);
  lds_stream<<<1024, 256, 0, stream>>>(logits, adj, ws);
  gram_band<<<1024, 512, 0, stream>>>(adj, nf, ws);
  finalize<<<1, 64, 0, stream>>>(ws, pcount, out);
}